// Round 4
// baseline (179.513 us; speedup 1.0000x reference)
//
#include <hip/hip_runtime.h>
#include <stdint.h>

// CRF loss: S=32768, L=512 — fused persistent kernel, R4.
// R4 vs R3: two-tile ping-pong in phase 1. R3 counters (MfmaUtil 15%,
// VALUBusy 21%, occupancy at cap) showed ~60% of each step idle: block-wide
// barriers lockstep all waves through alternating {MFMA burst | renorm chain}
// so the matrix pipe sleeps during renorm and vice versa. Now each block owns
// TWO independent 16-column tiles (32 chunks of CH=8); every barrier interval
// runs tile X's 32-MFMA burst CONCURRENTLY with tile Y's renorm (disjoint
// regs/LDS) -> MFMA and VALU/trans overlap. Same total MFMA work, same
// barrier count, ~2x work per interval.
//   P0: fp8 A-fragments of E'=2*exp(T), E'^T; gold-path partials.
//   P1: ping-pong chunked forward/backward (4096 chunks of 8 steps).
//   P2: per-chunk lse stitch terms — one WAVE per chunk (all 256 blocks).
//   P3: block 0 final reduction -> out[0].

#define S_LEN 32768
#define L 512
#define CH 8
#define NCF 4096            // chunks (c = 0..4095)
#define NB  256             // blocks; 128 fwd + 128 bwd
#define TPB 1024
#define LN448 6.104793232f
#define LN2   0.6931471806f

// ws layout (bytes), total ~8.95 MB
#define OFF_EAF  0                       // 256 KB: A-frag fp8 of E'   (fwd)
#define OFF_EAB  (256*1024)              // 256 KB: A-frag fp8 of E'^T (bwd)
#define OFF_G    (512*1024)              // 4096*512 bf16 (4 MB)
#define OFF_H    (OFF_G + NCF*512*2)     // 4096*512 bf16 (4 MB, row 0 unused)
#define OFF_LSE  (OFF_H + NCF*512*2)     // 2*4096+1 f32
#define OFF_GOLD (OFF_LSE + (2*NCF+8)*4) // 256 f32 gold partials
#define OFF_BAR  (OFF_GOLD + 1024)       // grid-barrier counter (memset to 0)

typedef float v4f __attribute__((ext_vector_type(4)));

__device__ __forceinline__ float b2f(unsigned short u){
  return __uint_as_float(((unsigned)u) << 16);
}
__device__ __forceinline__ unsigned short f2b(float x){
  unsigned u = __float_as_uint(x);
  return (unsigned short)((u + 0x7fffu + ((u >> 16) & 1u)) >> 16);
}
__device__ __forceinline__ unsigned char to_fp8(float v){
  int u = __builtin_amdgcn_cvt_pk_fp8_f32(v, v, 0, false);
  return (unsigned char)(u & 0xff);
}

// sc1 (LLC-direct) stores for cross-phase payloads: no L2 writeback needed.
__device__ __forceinline__ void stg_u8(unsigned char* p, unsigned char v){
  __hip_atomic_store(p, v, __ATOMIC_RELAXED, __HIP_MEMORY_SCOPE_AGENT);
}
__device__ __forceinline__ void stg_u64(unsigned long long* p, unsigned long long v){
  __hip_atomic_store(p, v, __ATOMIC_RELAXED, __HIP_MEMORY_SCOPE_AGENT);
}
__device__ __forceinline__ void stg_f32(float* p, float v){
  __hip_atomic_store(p, v, __ATOMIC_RELAXED, __HIP_MEMORY_SCOPE_AGENT);
}

// workgroup barrier that does NOT drain vmcnt (prefetched global loads stay
// in flight). lgkmcnt(0) makes LDS writes visible; sched_barrier pins order.
__device__ __forceinline__ void lds_sync(){
  asm volatile("s_waitcnt lgkmcnt(0)" ::: "memory");
  __builtin_amdgcn_sched_barrier(0);
  __builtin_amdgcn_s_barrier();
  __builtin_amdgcn_sched_barrier(0);
}

// grid barrier (R2 scheme): payloads at LLC via sc1 stores + __syncthreads
// vmcnt drain; relaxed polls; ONE acquire fence (L2 inv) per block.
__device__ __forceinline__ void grid_bar(unsigned* bar, unsigned target){
  __syncthreads();
  if (threadIdx.x == 0) {
    __hip_atomic_fetch_add(bar, 1u, __ATOMIC_RELAXED, __HIP_MEMORY_SCOPE_AGENT);
    unsigned it = 0;
    while (__hip_atomic_load(bar, __ATOMIC_RELAXED, __HIP_MEMORY_SCOPE_AGENT) < target) {
      __builtin_amdgcn_s_sleep(8);
      if ((++it & 255u) == 0u)
        (void)__hip_atomic_load(bar, __ATOMIC_ACQUIRE, __HIP_MEMORY_SCOPE_AGENT);
    }
    __builtin_amdgcn_fence(__ATOMIC_ACQUIRE, "agent");
  }
  __syncthreads();
}

__device__ __forceinline__ float blockSum(float v, float* sred){
  #pragma unroll
  for (int off = 32; off >= 1; off >>= 1) v += __shfl_xor(v, off);
  int wid = threadIdx.x >> 6, lane = threadIdx.x & 63;
  if (lane == 0) sred[wid] = v;
  __syncthreads();
  if (threadIdx.x < 16) {
    float t = sred[threadIdx.x];
    t += __shfl_xor(t, 8); t += __shfl_xor(t, 4);
    t += __shfl_xor(t, 2); t += __shfl_xor(t, 1);
    if (threadIdx.x == 0) sred[16] = t;
  }
  __syncthreads();
  float r = sred[16];
  __syncthreads();
  return r;
}

__device__ __forceinline__ float waveMax(float v){
  #pragma unroll
  for (int off = 32; off >= 1; off >>= 1) v = fmaxf(v, __shfl_xor(v, off));
  return v;
}
__device__ __forceinline__ float waveSum(float v){
  #pragma unroll
  for (int off = 32; off >= 1; off >>= 1) v += __shfl_xor(v, off);
  return v;
}

extern "C" __global__ __launch_bounds__(TPB, 4)
void crf_fused(const float* __restrict__ logit,
               const int* __restrict__ labels,
               const float* __restrict__ T,
               float* __restrict__ out,
               unsigned char* __restrict__ EAf,
               unsigned char* __restrict__ EAb,
               unsigned short* __restrict__ G,
               unsigned short* __restrict__ H,
               float* __restrict__ lsebuf,
               float* __restrict__ part,
               unsigned* __restrict__ bar){
  __shared__ __align__(16) unsigned char Pl[2*8192];   // A at 0, B at 8192
  __shared__ float sPartA[16][20];
  __shared__ float sPartB[16][20];
  __shared__ float sredG[17];

  const int tidx = threadIdx.x;

  // ---------------- Phase 0: prep (E' fragments) + gold partials -----------
  {
    int tid = blockIdx.x*TPB + tidx;     // 0..262143, exactly one pass
    int r    = tid & 7;
    int lane = (tid >> 3) & 63;
    int kt   = (tid >> 9) & 15;
    int R16  = tid >> 13;                // 0..31
    int j = R16*16 + (lane & 15);
    int i = kt*32 + ((lane >> 4) << 3) + r;
    stg_u8(EAf + tid, to_fp8(2.0f * __expf(T[j*L + i])));  // E'[j][i]
    stg_u8(EAb + tid, to_fp8(2.0f * __expf(T[i*L + j])));  // E'^T[j][i]
  }
  {
    float acc = 0.f;
    if (tidx < 128) {
      int t = blockIdx.x*128 + tidx;     // covers 0..32767 exactly
      int yt = labels[t];
      float v = logit[(size_t)t*L + yt];
      if (t > 0) v += T[yt*L + labels[t-1]];
      acc = v;
    }
    float s = blockSum(acc, sredG);
    if (tidx == 0) stg_f32(part + blockIdx.x, s);
  }
  grid_bar(bar, NB);

  // ---------------- Phase 1: ping-pong chunked forward/backward ------------
  {
    const int w    = tidx >> 6;                    // wave 0..15, owns 32 rows
    const int lane = tidx & 63;
    const int quad = lane >> 4;
    const int cl   = lane & 15;                    // MFMA column within tile
    const bool fwd = (blockIdx.x < NB/2);
    const int  b   = fwd ? blockIdx.x : (blockIdx.x - NB/2);
    const int  cgA = fwd ? (b*32 + cl)      : (1 + b*32 + cl);
    const int  cgB = fwd ? (b*32 + 16 + cl) : (1 + b*32 + 16 + cl);
    const int  cgcA = min(cgA, NCF-1);
    const int  cgcB = min(cgB, NCF-1);
    const bool isc0 = fwd && (cgA == 0);           // only tile A can hold c=0
    const int  jrow0 = w*32 + quad*4;

    // E' A-fragments: 32 longs = 64 regs per wave (shared by both tiles)
    const long* EAp = (const long*)(fwd ? EAf : EAb);
    long eA[2][16];
    #pragma unroll
    for (int mt = 0; mt < 2; ++mt)
      #pragma unroll
      for (int kt = 0; kt < 16; ++kt)
        eA[mt][kt] = EAp[(((w*2 + mt)*16) + kt)*64 + lane];

    // precomputed LDS addresses (same within-tile layout for A and B)
    int pladdr0, pladdr1;
    {
      int r0 = jrow0;
      pladdr0 = (r0 >> 5)*512 + ((((r0 >> 3) & 3)*16 + cl) << 3) + (r0 & 7);
      r0 = jrow0 + 16;
      pladdr1 = (r0 >> 5)*512 + ((((r0 >> 3) & 3)*16 + cl) << 3) + (r0 & 7);
    }
    const int bbbase = lane*8;

    // feature pointers + prefetch buffers
    const int dstep = fwd ? L : -L;
    const float* lpA = logit + (size_t)(fwd ? cgcA*CH : cgcA*CH + CH - 2)*L + jrow0;
    const float* lpB = logit + (size_t)(fwd ? cgcB*CH : cgcB*CH + CH - 2)*L + jrow0;
    float4 pA0, pA1, pB0, pB1;

    v4f vA0, vA1, vB0, vB1;
    if (fwd) {
      vA0 = (v4f){1.f,1.f,1.f,1.f}; vA1 = vA0; vB0 = vA0; vB1 = vA0;
    } else {
      const float* ip = logit + (size_t)(cgcA*CH + CH - 1)*L + jrow0;
      float4 x0 = *(const float4*)ip, x1 = *(const float4*)(ip + 16);
      vA0 = (v4f){__expf(x0.x),__expf(x0.y),__expf(x0.z),__expf(x0.w)};
      vA1 = (v4f){__expf(x1.x),__expf(x1.y),__expf(x1.z),__expf(x1.w)};
      ip = logit + (size_t)(cgcB*CH + CH - 1)*L + jrow0;
      x0 = *(const float4*)ip; x1 = *(const float4*)(ip + 16);
      vB0 = (v4f){__expf(x0.x),__expf(x0.y),__expf(x0.z),__expf(x0.w)};
      vB1 = (v4f){__expf(x1.x),__expf(x1.y),__expf(x1.z),__expf(x1.w)};
    }
    float mA = 0.0f, mB = 0.0f;

    pA0 = *(const float4*)lpA; pA1 = *(const float4*)(lpA + 16);
    pB0 = *(const float4*)lpB; pB1 = *(const float4*)(lpB + 16);

    // --- helpers (inlined lambdas; all indices static) ---
    auto lmax_do = [&](v4f& x0, v4f& x1, float* spw){
      float mx = fmaxf(fmaxf(fmaxf(x0[0],x0[1]),fmaxf(x0[2],x0[3])),
                       fmaxf(fmaxf(x1[0],x1[1]),fmaxf(x1[2],x1[3])));
      mx = fmaxf(mx, __shfl_xor(mx, 16));
      mx = fmaxf(mx, __shfl_xor(mx, 32));
      if (quad == 0) *spw = mx;
    };
    auto s2_do = [&](v4f& x0, v4f& x1, const float* spbase, int plbase, float& m){
      const float4* sp4 = (const float4*)spbase;
      float4 q0 = sp4[0], q1 = sp4[1], q2 = sp4[2], q3 = sp4[3];
      float M = fmaxf(fmaxf(fmaxf(fmaxf(q0.x,q0.y),fmaxf(q0.z,q0.w)),
                            fmaxf(fmaxf(q1.x,q1.y),fmaxf(q1.z,q1.w))),
                      fmaxf(fmaxf(fmaxf(q2.x,q2.y),fmaxf(q2.z,q2.w)),
                            fmaxf(fmaxf(q3.x,q3.y),fmaxf(q3.z,q3.w))));
      float sc = 448.0f / M;
      int u0 = __builtin_amdgcn_cvt_pk_fp8_f32(x0[0]*sc, x0[1]*sc, 0, false);
      u0     = __builtin_amdgcn_cvt_pk_fp8_f32(x0[2]*sc, x0[3]*sc, u0, true);
      *(int*)&Pl[plbase + pladdr0] = u0;
      int u1 = __builtin_amdgcn_cvt_pk_fp8_f32(x1[0]*sc, x1[1]*sc, 0, false);
      u1     = __builtin_amdgcn_cvt_pk_fp8_f32(x1[2]*sc, x1[3]*sc, u1, true);
      *(int*)&Pl[plbase + pladdr1] = u1;
      m += __logf(M) - LN448;
    };
    auto mfma_do = [&](int plbase, v4f& o0, v4f& o1){
      o0 = (v4f){0.f,0.f,0.f,0.f}; o1 = (v4f){0.f,0.f,0.f,0.f};
      const unsigned char* plr = &Pl[plbase + bbbase];
      #pragma unroll
      for (int kt = 0; kt < 16; ++kt) {
        long bb = *(const long*)(plr + kt*512);
        o0 = __builtin_amdgcn_mfma_f32_16x16x32_fp8_fp8(eA[0][kt], bb, o0, 0, 0, 0);
        o1 = __builtin_amdgcn_mfma_f32_16x16x32_fp8_fp8(eA[1][kt], bb, o1, 0, 0, 0);
      }
    };
    auto store_out = [&](v4f& x0, v4f& x1, float m, int cg){
      if (cg <= NCF-1) {
        unsigned short* dst = (fwd ? G : H) + (size_t)cg*L + jrow0;
        unsigned long long pv =
             (unsigned long long)f2b(__logf(x0[0]) + m)
          | ((unsigned long long)f2b(__logf(x0[1]) + m) << 16)
          | ((unsigned long long)f2b(__logf(x0[2]) + m) << 32)
          | ((unsigned long long)f2b(__logf(x0[3]) + m) << 48);
        stg_u64((unsigned long long*)dst, pv);
        pv = (unsigned long long)f2b(__logf(x1[0]) + m)
          | ((unsigned long long)f2b(__logf(x1[1]) + m) << 16)
          | ((unsigned long long)f2b(__logf(x1[2]) + m) << 32)
          | ((unsigned long long)f2b(__logf(x1[3]) + m) << 48);
        stg_u64((unsigned long long*)(dst + 16), pv);
      }
    };

    // --- prologue: init renorm of both tiles; pull A one half-step ahead ---
    lmax_do(vA0, vA1, &sPartA[cl][w]);
    lmax_do(vB0, vB1, &sPartB[cl][w]);
    lds_sync();
    s2_do(vA0, vA1, &sPartA[cl][0], 0, mA);        // PlA ready
    lds_sync();

    // --- steady loop: k = 0..6 (uniform; all steps here use features) ------
    for (int k = 0; k < CH-1; ++k) {
      // even half: S1(A,k) ∥ S2(B, k-1/init)
      {
        v4f a0, a1;
        mfma_do(0, a0, a1);                         // reads PlA
        s2_do(vB0, vB1, &sPartB[cl][0], 8192, mB);  // writes PlB
        float f0=__expf(pA0.x), f1=__expf(pA0.y), f2=__expf(pA0.z), f3=__expf(pA0.w);
        float g0=__expf(pA1.x), g1=__expf(pA1.y), g2=__expf(pA1.z), g3=__expf(pA1.w);
        vA0 = (v4f){a0[0]*f0, a0[1]*f1, a0[2]*f2, a0[3]*f3};
        vA1 = (v4f){a1[0]*g0, a1[1]*g1, a1[2]*g2, a1[3]*g3};
        if (k == 0 && isc0) {          // chunk 0 exact anchor: alpha_0 = exp(feat_0)
          vA0 = (v4f){f0,f1,f2,f3}; vA1 = (v4f){g0,g1,g2,g3}; mA = 0.0f;
        }
        lpA += dstep;                  // prefetch step k+1 (dead-but-safe for
        pA0 = *(const float4*)lpA;     // bwd k=6; stays in flight across bars)
        pA1 = *(const float4*)(lpA + 16);
        lmax_do(vA0, vA1, &sPartA[cl][w]);
        lds_sync();
      }
      // odd half: S1(B,k) ∥ S2(A,k)
      {
        v4f b0, b1;
        mfma_do(8192, b0, b1);                      // reads PlB
        s2_do(vA0, vA1, &sPartA[cl][0], 0, mA);     // writes PlA
        float f0=__expf(pB0.x), f1=__expf(pB0.y), f2=__expf(pB0.z), f3=__expf(pB0.w);
        float g0=__expf(pB1.x), g1=__expf(pB1.y), g2=__expf(pB1.z), g3=__expf(pB1.w);
        vB0 = (v4f){b0[0]*f0, b0[1]*f1, b0[2]*f2, b0[3]*f3};
        vB1 = (v4f){b1[0]*g0, b1[1]*g1, b1[2]*g2, b1[3]*g3};
        lpB += dstep;
        pB0 = *(const float4*)lpB;
        pB1 = *(const float4*)(lpB + 16);
        lmax_do(vB0, vB1, &sPartB[cl][w]);
        lds_sync();
      }
    }

    // --- peeled last step k = CH-1 (fwd: with features; bwd: bare E^T) -----
    {
      v4f a0, a1;
      mfma_do(0, a0, a1);
      s2_do(vB0, vB1, &sPartB[cl][0], 8192, mB);    // S2(B, CH-2)
      if (fwd) {
        float f0=__expf(pA0.x), f1=__expf(pA0.y), f2=__expf(pA0.z), f3=__expf(pA0.w);
        float g0=__expf(pA1.x), g1=__expf(pA1.y), g2=__expf(pA1.z), g3=__expf(pA1.w);
        vA0 = (v4f){a0[0]*f0, a0[1]*f1, a0[2]*f2, a0[3]*f3};
        vA1 = (v4f){a1[0]*g0, a1[1]*g1, a1[2]*g2, a1[3]*g3};
      } else { vA0 = a0; vA1 = a1; }
      // folded E'=2E compensation: CH steps (CH-1 for the anchored column)
      store_out(vA0, vA1, mA - (isc0 ? (CH-1) : CH)*LN2, cgA);
      lds_sync();
      v4f b0, b1;
      mfma_do(8192, b0, b1);                        // reads PlB (just written)
      if (fwd) {
        float f0=__expf(pB0.x), f1=__expf(pB0.y), f2=__expf(pB0.z), f3=__expf(pB0.w);
        float g0=__expf(pB1.x), g1=__expf(pB1.y), g2=__expf(pB1.z), g3=__expf(pB1.w);
        vB0 = (v4f){b0[0]*f0, b0[1]*f1, b0[2]*f2, b0[3]*f3};
        vB1 = (v4f){b1[0]*g0, b1[1]*g1, b1[2]*g2, b1[3]*g3};
      } else { vB0 = b0; vB1 = b1; }
      store_out(vB0, vB1, mB - CH*LN2, cgB);
    }
  }
  grid_bar(bar, 2*NB);

  // ---------------- Phase 2: stitch lse terms — one WAVE per chunk ---------
  {
    const int w    = tidx >> 6;
    const int lane = tidx & 63;
    const int g    = blockIdx.x*16 + w;            // 0..4095
    const int j8   = lane*8;
    if (g == 0) {
      const unsigned short* p = G + (size_t)(NCF-1)*L + j8;
      ushort4 a = *(const ushort4*)p, bq = *(const ushort4*)(p + 4);
      float v[8] = { b2f(a.x),b2f(a.y),b2f(a.z),b2f(a.w),
                     b2f(bq.x),b2f(bq.y),b2f(bq.z),b2f(bq.w) };
      float mx = v[0];
      #pragma unroll
      for (int r = 1; r < 8; ++r) mx = fmaxf(mx, v[r]);
      mx = waveMax(mx);
      float s = 0.f;
      #pragma unroll
      for (int r = 0; r < 8; ++r) s += __expf(v[r] - mx);
      s = waveSum(s);
      if (lane == 0) stg_f32(lsebuf + 2*NCF, mx + __logf(s));
    } else {
      const unsigned short* hp = H + (size_t)g*L + j8;
      const unsigned short* gp = G + (size_t)(g-1)*L + j8;
      ushort4 ha = *(const ushort4*)hp, hb = *(const ushort4*)(hp + 4);
      ushort4 ga = *(const ushort4*)gp, gb = *(const ushort4*)(gp + 4);
      float hv[8] = { b2f(ha.x),b2f(ha.y),b2f(ha.z),b2f(ha.w),
                      b2f(hb.x),b2f(hb.y),b2f(hb.z),b2f(hb.w) };
      float gv[8] = { b2f(ga.x),b2f(ga.y),b2f(ga.z),b2f(ga.w),
                      b2f(gb.x),b2f(gb.y),b2f(gb.z),b2f(gb.w) };
      float m1 = -3.0e38f, m2 = -3.0e38f;
      #pragma unroll
      for (int r = 0; r < 8; ++r) {
        float a = hv[r] + gv[r];
        m1 = fmaxf(m1, a); m2 = fmaxf(m2, hv[r]);
      }
      m1 = waveMax(m1); m2 = waveMax(m2);
      float s1 = 0.f, s2 = 0.f;
      #pragma unroll
      for (int r = 0; r < 8; ++r) {
        s1 += __expf(hv[r] + gv[r] - m1);
        s2 += __expf(hv[r] - m2);
      }
      s1 = waveSum(s1); s2 = waveSum(s2);
      if (lane == 0) {
        stg_f32(lsebuf + g,       m1 + __logf(s1));
        stg_f32(lsebuf + NCF + g, m2 + __logf(s2));
      }
    }
  }
  grid_bar(bar, 3*NB);

  // ---------------- Phase 3: final reduction (block 0 only) ----------------
  if (blockIdx.x == 0) {
    float acc = 0.f;
    for (int c = tidx; c < NCF; c += TPB)
      if (c >= 1) acc += lsebuf[c] - lsebuf[NCF + c];
    if (tidx < NB) acc -= part[tidx];
    float s = blockSum(acc, sredG);
    if (tidx == 0) out[0] = lsebuf[2*NCF] + s;
  }
}

extern "C" void kernel_launch(void* const* d_in, const int* in_sizes, int n_in,
                              void* d_out, int out_size, void* d_ws, size_t ws_size,
                              hipStream_t stream){
  const float* logit = (const float*)d_in[0];
  const int* labels  = (const int*)d_in[1];
  const float* T     = (const float*)d_in[2];
  char* ws = (char*)d_ws;

  hipMemsetAsync(ws + OFF_BAR, 0, 64, stream);     // zero grid-barrier counter
  crf_fused<<<NB, TPB, 0, stream>>>(
      logit, labels, T, (float*)d_out,
      (unsigned char*)(ws + OFF_EAF), (unsigned char*)(ws + OFF_EAB),
      (unsigned short*)(ws + OFF_G), (unsigned short*)(ws + OFF_H),
      (float*)(ws + OFF_LSE), (float*)(ws + OFF_GOLD),
      (unsigned*)(ws + OFF_BAR));
}

// Round 5
// 156.476 us; speedup vs baseline: 1.1472x; 1.1472x over previous
//
#include <hip/hip_runtime.h>
#include <stdint.h>

// CRF loss: S=32768, L=512 — fused persistent kernel, R5.
// R5 vs R3/R4: R4's two-tile ping-pong spilled (FETCH/WRITE +19MB symmetric
// = scratch traffic) — reverted. R3's real limit was the logit gather being
// LATENCY-bound: 2 outstanding 16B loads/wave -> ~0.85 TB/s (Little's law),
// and P1 must stream 67 MB. Fix: 3-deep LDS feature ring staged with
// global_load_lds (zero VGPR cost; per-lane global src = coalesced 1KB/wave
// bursts of each chunk's OWN contiguous row). Counted vmcnt(2) at the step
// barrier keeps 2 steps of staging in flight (T4: never drain to 0).
// XOR swizzle (involution on pre-swizzled global source, rule #21) kills the
// 16-way stride-2048 bank conflict on the feature ds_reads.
// Phases (256 blocks x 1024 thr, dynamic LDS 116KB, 3 LLC grid barriers):
//   P0: fp8 A-fragments of E'=2*exp(T), E'^T; gold-path partials.
//   P1: chunked fwd/bwd, 16 MFMA columns/block, LDS-staged features.
//   P2: per-chunk lse stitch terms — one WAVE per chunk (blocks 0..127).
//   P3: block 0 final reduction -> out[0].

#define S_LEN 32768
#define L 512
#define CH 16
#define NCF 2048            // chunks (c = 0..2047)
#define NB  256             // blocks; 128 fwd + 128 bwd
#define TPB 1024
#define LN448 6.104793232f
#define LN2   0.6931471806f

// ws layout (bytes)
#define OFF_EAF  0                       // 256 KB: A-frag fp8 of E'   (fwd)
#define OFF_EAB  (256*1024)              // 256 KB: A-frag fp8 of E'^T (bwd)
#define OFF_G    (512*1024)              // 2048*512 bf16 (2 MB)
#define OFF_H    (OFF_G + 2048*512*2)    // 2048*512 bf16 (2 MB, row 0 unused)
#define OFF_LSE  (OFF_H + 2048*512*2)    // 4097 f32
#define OFF_GOLD (OFF_LSE + 4104*4)      // 256 f32 gold partials
#define OFF_BAR  (OFF_GOLD + 1024)       // grid-barrier counter (memset to 0)

// dynamic LDS layout (bytes)
#define PL_OFF   0                       // 2*8192 fp8 P double-buffer
#define SP_OFF   16384                   // sPart[16][20] f32
#define SR_OFF   17664                   // sred[17] f32
#define LF_OFF   18432                   // 3*32768 feature ring
#define SMEM_TOTAL (18432 + 3*32768)     // 116736

typedef float v4f __attribute__((ext_vector_type(4)));

__device__ __forceinline__ float b2f(unsigned short u){
  return __uint_as_float(((unsigned)u) << 16);
}
__device__ __forceinline__ unsigned short f2b(float x){
  unsigned u = __float_as_uint(x);
  return (unsigned short)((u + 0x7fffu + ((u >> 16) & 1u)) >> 16);
}
__device__ __forceinline__ unsigned char to_fp8(float v){
  int u = __builtin_amdgcn_cvt_pk_fp8_f32(v, v, 0, false);
  return (unsigned char)(u & 0xff);
}

// sc1 (LLC-direct) stores for cross-phase payloads: no L2 writeback needed.
__device__ __forceinline__ void stg_u8(unsigned char* p, unsigned char v){
  __hip_atomic_store(p, v, __ATOMIC_RELAXED, __HIP_MEMORY_SCOPE_AGENT);
}
__device__ __forceinline__ void stg_u64(unsigned long long* p, unsigned long long v){
  __hip_atomic_store(p, v, __ATOMIC_RELAXED, __HIP_MEMORY_SCOPE_AGENT);
}
__device__ __forceinline__ void stg_f32(float* p, float v){
  __hip_atomic_store(p, v, __ATOMIC_RELAXED, __HIP_MEMORY_SCOPE_AGENT);
}

// async global->LDS, 16B per lane; dst = wave-uniform base (HW adds lane*16),
// src is per-lane.
__device__ __forceinline__ void gl2lds16(const void* g, void* l){
  __builtin_amdgcn_global_load_lds(
      (const __attribute__((address_space(1))) void*)g,
      (__attribute__((address_space(3))) void*)l, 16, 0, 0);
}

// workgroup barrier, LDS-visibility only (no vmcnt drain).
__device__ __forceinline__ void lds_sync(){
  asm volatile("s_waitcnt lgkmcnt(0)" ::: "memory");
  __builtin_amdgcn_sched_barrier(0);
  __builtin_amdgcn_s_barrier();
  __builtin_amdgcn_sched_barrier(0);
}
// step-end barrier: LDS visible + counted vmcnt — allow 2 staging issues
// (the newest step's) to stay in flight; the step-before's are done.
__device__ __forceinline__ void step_sync(){
  asm volatile("s_waitcnt vmcnt(2) lgkmcnt(0)" ::: "memory");
  __builtin_amdgcn_sched_barrier(0);
  __builtin_amdgcn_s_barrier();
  __builtin_amdgcn_sched_barrier(0);
}

// grid barrier (R2 scheme): payloads at LLC via sc1 stores + __syncthreads
// vmcnt drain; relaxed polls; ONE acquire fence (L2 inv) per block.
__device__ __forceinline__ void grid_bar(unsigned* bar, unsigned target){
  __syncthreads();
  if (threadIdx.x == 0) {
    __hip_atomic_fetch_add(bar, 1u, __ATOMIC_RELAXED, __HIP_MEMORY_SCOPE_AGENT);
    unsigned it = 0;
    while (__hip_atomic_load(bar, __ATOMIC_RELAXED, __HIP_MEMORY_SCOPE_AGENT) < target) {
      __builtin_amdgcn_s_sleep(8);
      if ((++it & 255u) == 0u)
        (void)__hip_atomic_load(bar, __ATOMIC_ACQUIRE, __HIP_MEMORY_SCOPE_AGENT);
    }
    __builtin_amdgcn_fence(__ATOMIC_ACQUIRE, "agent");
  }
  __syncthreads();
}

__device__ __forceinline__ float blockSum(float v, float* sred){
  #pragma unroll
  for (int off = 32; off >= 1; off >>= 1) v += __shfl_xor(v, off);
  int wid = threadIdx.x >> 6, lane = threadIdx.x & 63;
  if (lane == 0) sred[wid] = v;
  __syncthreads();
  if (threadIdx.x < 16) {
    float t = sred[threadIdx.x];
    t += __shfl_xor(t, 8); t += __shfl_xor(t, 4);
    t += __shfl_xor(t, 2); t += __shfl_xor(t, 1);
    if (threadIdx.x == 0) sred[16] = t;
  }
  __syncthreads();
  float r = sred[16];
  __syncthreads();
  return r;
}

__device__ __forceinline__ float waveMax(float v){
  #pragma unroll
  for (int off = 32; off >= 1; off >>= 1) v = fmaxf(v, __shfl_xor(v, off));
  return v;
}
__device__ __forceinline__ float waveSum(float v){
  #pragma unroll
  for (int off = 32; off >= 1; off >>= 1) v += __shfl_xor(v, off);
  return v;
}

extern "C" __global__ __launch_bounds__(TPB, 4)
void crf_fused(const float* __restrict__ logit,
               const int* __restrict__ labels,
               const float* __restrict__ T,
               float* __restrict__ out,
               unsigned char* __restrict__ EAf,
               unsigned char* __restrict__ EAb,
               unsigned short* __restrict__ G,
               unsigned short* __restrict__ H,
               float* __restrict__ lsebuf,
               float* __restrict__ part,
               unsigned* __restrict__ bar){
  extern __shared__ __align__(16) char smem[];
  unsigned char* Pl = (unsigned char*)(smem + PL_OFF);
  float (*sPart)[20] = (float(*)[20])(smem + SP_OFF);
  float* sredG       = (float*)(smem + SR_OFF);
  char*  LF          = smem + LF_OFF;

  const int tidx = threadIdx.x;

  // ---------------- Phase 0: prep (E' fragments) + gold partials -----------
  // A-frag layout: byte (R16*16+kt)*512 + lane*8 + r holds
  //   Mat[m = R16*16+(lane&15)][k = kt*32+(lane>>4)*8+r]
  {
    int tid = blockIdx.x*TPB + tidx;     // 0..262143, exactly one pass
    int r    = tid & 7;
    int lane = (tid >> 3) & 63;
    int kt   = (tid >> 9) & 15;
    int R16  = tid >> 13;                // 0..31
    int j = R16*16 + (lane & 15);
    int i = kt*32 + ((lane >> 4) << 3) + r;
    stg_u8(EAf + tid, to_fp8(2.0f * __expf(T[j*L + i])));  // E'[j][i]
    stg_u8(EAb + tid, to_fp8(2.0f * __expf(T[i*L + j])));  // E'^T[j][i]
  }
  {
    float acc = 0.f;
    if (tidx < 128) {
      int t = blockIdx.x*128 + tidx;     // covers 0..32767 exactly
      int yt = labels[t];
      float v = logit[(size_t)t*L + yt];
      if (t > 0) v += T[yt*L + labels[t-1]];
      acc = v;
    }
    float s = blockSum(acc, sredG);
    if (tidx == 0) stg_f32(part + blockIdx.x, s);
  }
  grid_bar(bar, NB);

  // ---------------- Phase 1: chunked forward/backward ----------------------
  {
    const int w    = tidx >> 6;                    // wave 0..15, owns 32 rows
    const int lane = tidx & 63;
    const int quad = lane >> 4;
    const int cl   = lane & 15;                    // MFMA column = chunk slot
    const bool fwd = (blockIdx.x < NB/2);
    const int  b   = fwd ? blockIdx.x : (blockIdx.x - NB/2);
    const int  cg  = fwd ? (b*16 + cl) : (1 + b*16 + cl);
    const int  cgc = min(cg, NCF-1);
    const bool isc0 = fwd && (cg == 0);
    const int  jrow0 = w*32 + quad*4;

    // wave-owned staging chunk (column index == wave id)
    const int  cgw  = fwd ? (b*16 + w) : (1 + b*16 + w);
    const int  cgcw = min(cgw, NCF-1);
    const unsigned swzw = (unsigned)((w & 7) << 4);
    const unsigned so   = ((unsigned)(lane*16)) ^ swzw;   // pre-swizzled src

    // E' A-fragments: 32 longs = 64 acc-regs per wave
    const long* EAp = (const long*)(fwd ? EAf : EAb);
    long eA[2][16];
    #pragma unroll
    for (int mt = 0; mt < 2; ++mt)
      #pragma unroll
      for (int kt = 0; kt < 16; ++kt)
        eA[mt][kt] = EAp[(((w*2 + mt)*16) + kt)*64 + lane];

    // LDS addresses (constant per thread)
    int pladdr0, pladdr1;
    {
      int r0 = jrow0;
      pladdr0 = (r0 >> 5)*512 + ((((r0 >> 3) & 3)*16 + cl) << 3) + (r0 & 7);
      r0 = jrow0 + 16;
      pladdr1 = (r0 >> 5)*512 + ((((r0 >> 3) & 3)*16 + cl) << 3) + (r0 & 7);
    }
    const int bbbase = lane*8;
    const int scl = (cl & 7) << 4;
    const int ib  = w*128 + quad*16;
    const int fa0 = cl*2048 + (ib ^ scl);          // swizzled feature reads
    const int fa1 = cl*2048 + ((ib + 64) ^ scl);

    // prologue staging: steps 0 and 1 (valid for both directions)
    {
      size_t t0 = (size_t)(fwd ? (cgcw*CH + 0) : (cgcw*CH + CH - 2 - 0));
      size_t t1 = (size_t)(fwd ? (cgcw*CH + 1) : (cgcw*CH + CH - 2 - 1));
      const char* r0p = (const char*)logit + t0*(L*4);
      const char* r1p = (const char*)logit + t1*(L*4);
      char* d0 = LF + 0*32768 + w*2048;
      char* d1 = LF + 1*32768 + w*2048;
      gl2lds16(r0p + so, d0);  gl2lds16(r0p + 1024 + so, d0 + 1024);
      gl2lds16(r1p + so, d1);  gl2lds16(r1p + 1024 + so, d1 + 1024);
    }

    // init v
    v4f v0, v1;
    if (fwd) {
      v0 = (v4f){1.f,1.f,1.f,1.f}; v1 = v0;
    } else {
      const float* ip = logit + (size_t)(cgc*CH + CH - 1)*L + jrow0;
      float4 x0 = *(const float4*)ip, x1 = *(const float4*)(ip + 16);
      v0 = (v4f){__expf(x0.x),__expf(x0.y),__expf(x0.z),__expf(x0.w)};
      v1 = (v4f){__expf(x1.x),__expf(x1.y),__expf(x1.z),__expf(x1.w)};
    }
    float m = 0.0f;
    int par = 0;
    int bo0 = 0, bo1 = 32768, bo2 = 2*32768;

    // initial renorm -> Pl[0]
    {
      float mx = fmaxf(fmaxf(fmaxf(v0[0],v0[1]),fmaxf(v0[2],v0[3])),
                       fmaxf(fmaxf(v1[0],v1[1]),fmaxf(v1[2],v1[3])));
      mx = fmaxf(mx, __shfl_xor(mx, 16));
      mx = fmaxf(mx, __shfl_xor(mx, 32));
      if (quad == 0) sPart[cl][w] = mx;
      lds_sync();
      const float4* sp4 = (const float4*)&sPart[cl][0];
      float4 q0 = sp4[0], q1 = sp4[1], q2 = sp4[2], q3 = sp4[3];
      float M = fmaxf(fmaxf(fmaxf(fmaxf(q0.x,q0.y),fmaxf(q0.z,q0.w)),
                            fmaxf(fmaxf(q1.x,q1.y),fmaxf(q1.z,q1.w))),
                      fmaxf(fmaxf(fmaxf(q2.x,q2.y),fmaxf(q2.z,q2.w)),
                            fmaxf(fmaxf(q3.x,q3.y),fmaxf(q3.z,q3.w))));
      float sc = 448.0f / M;
      int u0 = __builtin_amdgcn_cvt_pk_fp8_f32(v0[0]*sc, v0[1]*sc, 0, false);
      u0     = __builtin_amdgcn_cvt_pk_fp8_f32(v0[2]*sc, v0[3]*sc, u0, true);
      *(int*)&Pl[pladdr0] = u0;
      int u1 = __builtin_amdgcn_cvt_pk_fp8_f32(v1[0]*sc, v1[1]*sc, 0, false);
      u1     = __builtin_amdgcn_cvt_pk_fp8_f32(v1[2]*sc, v1[3]*sc, u1, true);
      *(int*)&Pl[pladdr1] = u1;
      m = __logf(M) - LN448;
      step_sync();                       // vmcnt(2): step-0 staging complete
    }

    for (int k = 0; k < CH; ++k) {
      const bool last = (k == CH-1);
      const bool useF = fwd || !last;

      // stage step k+2 into bo2 (buffer freed by step k-1's reads)
      {
        const int ks = k + 2;
        const bool ok = fwd ? (ks <= CH-1) : (ks <= CH-2);
        if (ok) {
          size_t t = (size_t)(fwd ? (cgcw*CH + ks) : (cgcw*CH + CH - 2 - ks));
          const char* row = (const char*)logit + t*(L*4);
          char* dst = LF + bo2 + w*2048;
          gl2lds16(row + so, dst);
          gl2lds16(row + 1024 + so, dst + 1024);
        }
      }

      // MFMA burst: full 512-row matvec for the 16 columns
      v4f a0 = (v4f){0.f,0.f,0.f,0.f};
      v4f a1 = (v4f){0.f,0.f,0.f,0.f};
      {
        const unsigned char* plr = Pl + par*8192 + bbbase;
        #pragma unroll
        for (int kt = 0; kt < 16; ++kt) {
          long bb = *(const long*)(plr + kt*512);
          a0 = __builtin_amdgcn_mfma_f32_16x16x32_fp8_fp8(eA[0][kt], bb, a0, 0, 0, 0);
          a1 = __builtin_amdgcn_mfma_f32_16x16x32_fp8_fp8(eA[1][kt], bb, a1, 0, 0, 0);
        }
      }

      if (useF) {
        const char* fb = LF + bo0;
        float4 q0 = *(const float4*)(fb + fa0);
        float4 q1 = *(const float4*)(fb + fa1);
        float f0=__expf(q0.x), f1=__expf(q0.y), f2=__expf(q0.z), f3=__expf(q0.w);
        float g0=__expf(q1.x), g1=__expf(q1.y), g2=__expf(q1.z), g3=__expf(q1.w);
        a0 = (v4f){a0[0]*f0, a0[1]*f1, a0[2]*f2, a0[3]*f3};
        a1 = (v4f){a1[0]*g0, a1[1]*g1, a1[2]*g2, a1[3]*g3};
        if (k == 0 && isc0) {          // chunk 0 exact anchor: alpha_0 = exp(feat_0)
          a0 = (v4f){f0,f1,f2,f3}; a1 = (v4f){g0,g1,g2,g3}; m = 0.0f;
        }
      }

      if (last) {
        if (cg <= NCF-1) {
          // folded E'=2E compensation: 16 steps (15 for the anchored chunk)
          float madj = m - (isc0 ? (float)(CH-1) : (float)CH) * LN2;
          unsigned short* dst = (fwd ? G : H) + (size_t)cg*L + jrow0;
          unsigned long long pv =
               (unsigned long long)f2b(__logf(a0[0]) + madj)
            | ((unsigned long long)f2b(__logf(a0[1]) + madj) << 16)
            | ((unsigned long long)f2b(__logf(a0[2]) + madj) << 32)
            | ((unsigned long long)f2b(__logf(a0[3]) + madj) << 48);
          stg_u64((unsigned long long*)dst, pv);
          pv = (unsigned long long)f2b(__logf(a1[0]) + madj)
            | ((unsigned long long)f2b(__logf(a1[1]) + madj) << 16)
            | ((unsigned long long)f2b(__logf(a1[2]) + madj) << 32)
            | ((unsigned long long)f2b(__logf(a1[3]) + madj) << 48);
          stg_u64((unsigned long long*)(dst + 16), pv);
        }
      } else {
        // renorm + fp8 quantize into Pl[par^1]
        float mx = fmaxf(fmaxf(fmaxf(a0[0],a0[1]),fmaxf(a0[2],a0[3])),
                         fmaxf(fmaxf(a1[0],a1[1]),fmaxf(a1[2],a1[3])));
        mx = fmaxf(mx, __shfl_xor(mx, 16));
        mx = fmaxf(mx, __shfl_xor(mx, 32));
        if (quad == 0) sPart[cl][w] = mx;
        lds_sync();
        const float4* sp4 = (const float4*)&sPart[cl][0];
        float4 q0 = sp4[0], q1 = sp4[1], q2 = sp4[2], q3 = sp4[3];
        float M = fmaxf(fmaxf(fmaxf(fmaxf(q0.x,q0.y),fmaxf(q0.z,q0.w)),
                              fmaxf(fmaxf(q1.x,q1.y),fmaxf(q1.z,q1.w))),
                        fmaxf(fmaxf(fmaxf(q2.x,q2.y),fmaxf(q2.z,q2.w)),
                              fmaxf(fmaxf(q3.x,q3.y),fmaxf(q3.z,q3.w))));
        float sc = 448.0f / M;
        int u0 = __builtin_amdgcn_cvt_pk_fp8_f32(a0[0]*sc, a0[1]*sc, 0, false);
        u0     = __builtin_amdgcn_cvt_pk_fp8_f32(a0[2]*sc, a0[3]*sc, u0, true);
        *(int*)&Pl[(par^1)*8192 + pladdr0] = u0;
        int u1 = __builtin_amdgcn_cvt_pk_fp8_f32(a1[0]*sc, a1[1]*sc, 0, false);
        u1     = __builtin_amdgcn_cvt_pk_fp8_f32(a1[2]*sc, a1[3]*sc, u1, true);
        *(int*)&Pl[(par^1)*8192 + pladdr1] = u1;
        m += __logf(M) - LN448;
        step_sync();                     // Pl visible; keep 2 staging in flight
        par ^= 1;
        int tmp = bo0; bo0 = bo1; bo1 = bo2; bo2 = tmp;
      }
    }
  }
  grid_bar(bar, 2*NB);

  // ---------------- Phase 2: stitch lse terms — one WAVE per chunk ---------
  if (blockIdx.x < 128) {
    const int w    = tidx >> 6;
    const int lane = tidx & 63;
    const int g    = blockIdx.x*16 + w;            // 0..2047
    const int j8   = lane*8;
    if (g == 0) {
      const unsigned short* p = G + (size_t)(NCF-1)*L + j8;
      ushort4 a = *(const ushort4*)p, bq = *(const ushort4*)(p + 4);
      float v[8] = { b2f(a.x),b2f(a.y),b2f(a.z),b2f(a.w),
                     b2f(bq.x),b2f(bq.y),b2f(bq.z),b2f(bq.w) };
      float mx = v[0];
      #pragma unroll
      for (int r = 1; r < 8; ++r) mx = fmaxf(mx, v[r]);
      mx = waveMax(mx);
      float s = 0.f;
      #pragma unroll
      for (int r = 0; r < 8; ++r) s += __expf(v[r] - mx);
      s = waveSum(s);
      if (lane == 0) stg_f32(lsebuf + 2*NCF, mx + __logf(s));
    } else {
      const unsigned short* hp = H + (size_t)g*L + j8;
      const unsigned short* gp = G + (size_t)(g-1)*L + j8;
      ushort4 ha = *(const ushort4*)hp, hb = *(const ushort4*)(hp + 4);
      ushort4 ga = *(const ushort4*)gp, gb = *(const ushort4*)(gp + 4);
      float hv[8] = { b2f(ha.x),b2f(ha.y),b2f(ha.z),b2f(ha.w),
                      b2f(hb.x),b2f(hb.y),b2f(hb.z),b2f(hb.w) };
      float gv[8] = { b2f(ga.x),b2f(ga.y),b2f(ga.z),b2f(ga.w),
                      b2f(gb.x),b2f(gb.y),b2f(gb.z),b2f(gb.w) };
      float m1 = -3.0e38f, m2 = -3.0e38f;
      #pragma unroll
      for (int r = 0; r < 8; ++r) {
        float a = hv[r] + gv[r];
        m1 = fmaxf(m1, a); m2 = fmaxf(m2, hv[r]);
      }
      m1 = waveMax(m1); m2 = waveMax(m2);
      float s1 = 0.f, s2 = 0.f;
      #pragma unroll
      for (int r = 0; r < 8; ++r) {
        s1 += __expf(hv[r] + gv[r] - m1);
        s2 += __expf(hv[r] - m2);
      }
      s1 = waveSum(s1); s2 = waveSum(s2);
      if (lane == 0) {
        stg_f32(lsebuf + g,       m1 + __logf(s1));
        stg_f32(lsebuf + NCF + g, m2 + __logf(s2));
      }
    }
  }
  grid_bar(bar, 3*NB);

  // ---------------- Phase 3: final reduction (block 0 only) ----------------
  if (blockIdx.x == 0) {
    float acc = 0.f;
    for (int c = tidx; c < NCF; c += TPB)
      if (c >= 1) acc += lsebuf[c] - lsebuf[NCF + c];
    if (tidx < NB) acc -= part[tidx];
    float s = blockSum(acc, sredG);
    if (tidx == 0) out[0] = lsebuf[2*NCF] + s;
  }
}

extern "C" void kernel_launch(void* const* d_in, const int* in_sizes, int n_in,
                              void* d_out, int out_size, void* d_ws, size_t ws_size,
                              hipStream_t stream){
  const float* logit = (const float*)d_in[0];
  const int* labels  = (const int*)d_in[1];
  const float* T     = (const float*)d_in[2];
  char* ws = (char*)d_ws;

  static bool attr_set = false;
  if (!attr_set) {
    hipFuncSetAttribute((const void*)crf_fused,
                        hipFuncAttributeMaxDynamicSharedMemorySize, SMEM_TOTAL);
    attr_set = true;
  }

  hipMemsetAsync(ws + OFF_BAR, 0, 64, stream);     // zero grid-barrier counter
  crf_fused<<<NB, TPB, SMEM_TOTAL, stream>>>(
      logit, labels, T, (float*)d_out,
      (unsigned char*)(ws + OFF_EAF), (unsigned char*)(ws + OFF_EAB),
      (unsigned short*)(ws + OFF_G), (unsigned short*)(ws + OFF_H),
      (float*)(ws + OFF_LSE), (float*)(ws + OFF_GOLD),
      (unsigned*)(ws + OFF_BAR));
}

// Round 7
// 131.894 us; speedup vs baseline: 1.3610x; 1.1864x over previous
//
#include <hip/hip_runtime.h>
#include <stdint.h>

// CRF loss: S=32768, L=512 — R6b: DE-fuse back to 4 dispatches (R6 + compile
// fix: missing `out` decl in kernel_launch).
// Evidence: harness overhead is FIXED (~70us) regardless of dispatch count
// (R1: 1 dispatch, 200 total; R0: 5 dispatches, 148.8 total); captured-graph
// inter-dispatch gaps are ~0-2us. Fusion bought nothing and cost: 3 LLC grid
// barriers (256-way same-line atomics + acquire fences), sc1 store hacks, and
// all phase observability. R3/R5 both sit at ~83us fused with ~50us
// unattributable between P1 and the rest. This round: identical P1 machinery
// (1024thr, 4 waves/SIMD, LDS feature ring w/ counted vmcnt, non-draining
// step barriers) as its own kernel; prep/lse/final as separate kernels with
// plain loads/stores (kernel-boundary coherence). Next round's rocprof rows
// attribute the time per phase directly.
//   crf_prep:   fp8 A-frags of E'=2*exp(T), E'^T; gold partials. 256x1024.
//   crf_chunks: chunked fwd/bwd, 16 MFMA cols/block, LDS-staged features.
//   crf_lse:    per-chunk stitch lse terms, one wave per chunk. 256x512.
//   crf_final:  reduction -> out[0]. 1x512.

#define S_LEN 32768
#define L 512
#define CH 16
#define NCF 2048            // chunks (c = 0..2047)
#define NB  256
#define TPB 1024
#define LN448 6.104793232f
#define LN2   0.6931471806f

// ws layout (bytes)
#define OFF_EAF  0                       // 256 KB: A-frag fp8 of E'   (fwd)
#define OFF_EAB  (256*1024)              // 256 KB: A-frag fp8 of E'^T (bwd)
#define OFF_G    (512*1024)              // 2048*512 bf16 (2 MB)
#define OFF_H    (OFF_G + 2048*512*2)    // 2048*512 bf16 (2 MB, row 0 unused)
#define OFF_LSE  (OFF_H + 2048*512*2)    // 4097 f32
#define OFF_GOLD (OFF_LSE + 4104*4)      // 256 f32 gold partials

// dynamic LDS layout for crf_chunks (bytes)
#define PL_OFF   0                       // 2*8192 fp8 P double-buffer
#define SP_OFF   16384                   // sPart[16][20] f32
#define LF_OFF   18432                   // 3*32768 feature ring
#define SMEM_TOTAL (18432 + 3*32768)     // 116736

typedef float v4f __attribute__((ext_vector_type(4)));

__device__ __forceinline__ float b2f(unsigned short u){
  return __uint_as_float(((unsigned)u) << 16);
}
__device__ __forceinline__ unsigned short f2b(float x){
  unsigned u = __float_as_uint(x);
  return (unsigned short)((u + 0x7fffu + ((u >> 16) & 1u)) >> 16);
}
__device__ __forceinline__ unsigned char to_fp8(float v){
  int u = __builtin_amdgcn_cvt_pk_fp8_f32(v, v, 0, false);
  return (unsigned char)(u & 0xff);
}

// async global->LDS, 16B per lane; dst = wave-uniform base (HW adds lane*16),
// src is per-lane.
__device__ __forceinline__ void gl2lds16(const void* g, void* l){
  __builtin_amdgcn_global_load_lds(
      (const __attribute__((address_space(1))) void*)g,
      (__attribute__((address_space(3))) void*)l, 16, 0, 0);
}

// workgroup barrier, LDS-visibility only (no vmcnt drain).
__device__ __forceinline__ void lds_sync(){
  asm volatile("s_waitcnt lgkmcnt(0)" ::: "memory");
  __builtin_amdgcn_sched_barrier(0);
  __builtin_amdgcn_s_barrier();
  __builtin_amdgcn_sched_barrier(0);
}
// step-end barrier: LDS visible + counted vmcnt — keep the newest 2 staging
// issues in flight (T4: never drain to 0 in the loop).
__device__ __forceinline__ void step_sync(){
  asm volatile("s_waitcnt vmcnt(2) lgkmcnt(0)" ::: "memory");
  __builtin_amdgcn_sched_barrier(0);
  __builtin_amdgcn_s_barrier();
  __builtin_amdgcn_sched_barrier(0);
}

__device__ __forceinline__ float waveMax(float v){
  #pragma unroll
  for (int off = 32; off >= 1; off >>= 1) v = fmaxf(v, __shfl_xor(v, off));
  return v;
}
__device__ __forceinline__ float waveSum(float v){
  #pragma unroll
  for (int off = 32; off >= 1; off >>= 1) v += __shfl_xor(v, off);
  return v;
}

// block sum for 16-wave (1024-thr) blocks; sred: float[17]
__device__ __forceinline__ float blockSum16(float v, float* sred){
  #pragma unroll
  for (int off = 32; off >= 1; off >>= 1) v += __shfl_xor(v, off);
  int wid = threadIdx.x >> 6, lane = threadIdx.x & 63;
  if (lane == 0) sred[wid] = v;
  __syncthreads();
  if (threadIdx.x < 16) {
    float t = sred[threadIdx.x];
    t += __shfl_xor(t, 8); t += __shfl_xor(t, 4);
    t += __shfl_xor(t, 2); t += __shfl_xor(t, 1);
    if (threadIdx.x == 0) sred[16] = t;
  }
  __syncthreads();
  float r = sred[16];
  __syncthreads();
  return r;
}
// block sum for 8-wave (512-thr) blocks; sred: float[9]
__device__ __forceinline__ float blockSum8(float v, float* sred){
  #pragma unroll
  for (int off = 32; off >= 1; off >>= 1) v += __shfl_xor(v, off);
  int wid = threadIdx.x >> 6, lane = threadIdx.x & 63;
  if (lane == 0) sred[wid] = v;
  __syncthreads();
  if (threadIdx.x < 8) {
    float t = sred[threadIdx.x];
    t += __shfl_xor(t, 4); t += __shfl_xor(t, 2); t += __shfl_xor(t, 1);
    if (threadIdx.x == 0) sred[8] = t;
  }
  __syncthreads();
  float r = sred[8];
  __syncthreads();
  return r;
}

// ---------------- prep: E' fragments + gold partials ----------------
// A-frag layout: byte (R16*16+kt)*512 + lane*8 + r holds
//   Mat[m = R16*16+(lane&15)][k = kt*32+(lane>>4)*8+r]
extern "C" __global__ __launch_bounds__(TPB)
void crf_prep(const float* __restrict__ logit,
              const int* __restrict__ labels,
              const float* __restrict__ T,
              unsigned char* __restrict__ EAf,
              unsigned char* __restrict__ EAb,
              float* __restrict__ part){
  __shared__ float sredG[17];
  const int tidx = threadIdx.x;
  {
    int tid = blockIdx.x*TPB + tidx;     // 0..262143, exactly one pass
    int r    = tid & 7;
    int lane = (tid >> 3) & 63;
    int kt   = (tid >> 9) & 15;
    int R16  = tid >> 13;                // 0..31
    int j = R16*16 + (lane & 15);
    int i = kt*32 + ((lane >> 4) << 3) + r;
    EAf[tid] = to_fp8(2.0f * __expf(T[j*L + i]));  // E'[j][i]
    EAb[tid] = to_fp8(2.0f * __expf(T[i*L + j]));  // E'^T[j][i]
  }
  {
    float acc = 0.f;
    if (tidx < 128) {
      int t = blockIdx.x*128 + tidx;     // covers 0..32767 exactly
      int yt = labels[t];
      float v = logit[(size_t)t*L + yt];
      if (t > 0) v += T[yt*L + labels[t-1]];
      acc = v;
    }
    float s = blockSum16(acc, sredG);
    if (tidx == 0) part[blockIdx.x] = s;
  }
}

// ---------------- chunks: the forward/backward recurrence ----------------
extern "C" __global__ __launch_bounds__(TPB, 4)
void crf_chunks(const float* __restrict__ logit,
                const unsigned char* __restrict__ EAf,
                const unsigned char* __restrict__ EAb,
                unsigned short* __restrict__ G,
                unsigned short* __restrict__ H){
  extern __shared__ __align__(16) char smem[];
  unsigned char* Pl  = (unsigned char*)(smem + PL_OFF);
  float (*sPart)[20] = (float(*)[20])(smem + SP_OFF);
  char*  LF          = smem + LF_OFF;

  const int tidx = threadIdx.x;
  const int w    = tidx >> 6;                    // wave 0..15, owns 32 rows
  const int lane = tidx & 63;
  const int quad = lane >> 4;
  const int cl   = lane & 15;                    // MFMA column = chunk slot
  const bool fwd = (blockIdx.x < NB/2);
  const int  b   = fwd ? blockIdx.x : (blockIdx.x - NB/2);
  const int  cg  = fwd ? (b*16 + cl) : (1 + b*16 + cl);
  const int  cgc = min(cg, NCF-1);
  const bool isc0 = fwd && (cg == 0);
  const int  jrow0 = w*32 + quad*4;

  // wave-owned staging chunk (column index == wave id)
  const int  cgw  = fwd ? (b*16 + w) : (1 + b*16 + w);
  const int  cgcw = min(cgw, NCF-1);
  const unsigned swzw = (unsigned)((w & 7) << 4);
  const unsigned so   = ((unsigned)(lane*16)) ^ swzw;   // pre-swizzled src

  // E' A-fragments: 32 longs = 64 acc-regs per wave
  const long* EAp = (const long*)(fwd ? EAf : EAb);
  long eA[2][16];
  #pragma unroll
  for (int mt = 0; mt < 2; ++mt)
    #pragma unroll
    for (int kt = 0; kt < 16; ++kt)
      eA[mt][kt] = EAp[(((w*2 + mt)*16) + kt)*64 + lane];

  // LDS addresses (constant per thread)
  int pladdr0, pladdr1;
  {
    int r0 = jrow0;
    pladdr0 = (r0 >> 5)*512 + ((((r0 >> 3) & 3)*16 + cl) << 3) + (r0 & 7);
    r0 = jrow0 + 16;
    pladdr1 = (r0 >> 5)*512 + ((((r0 >> 3) & 3)*16 + cl) << 3) + (r0 & 7);
  }
  const int bbbase = lane*8;
  const int scl = (cl & 7) << 4;
  const int ib  = w*128 + quad*16;
  const int fa0 = cl*2048 + (ib ^ scl);          // swizzled feature reads
  const int fa1 = cl*2048 + ((ib + 64) ^ scl);

  // prologue staging: steps 0 and 1 (valid for both directions)
  {
    size_t t0 = (size_t)(fwd ? (cgcw*CH + 0) : (cgcw*CH + CH - 2 - 0));
    size_t t1 = (size_t)(fwd ? (cgcw*CH + 1) : (cgcw*CH + CH - 2 - 1));
    const char* r0p = (const char*)logit + t0*(L*4);
    const char* r1p = (const char*)logit + t1*(L*4);
    char* d0 = LF + 0*32768 + w*2048;
    char* d1 = LF + 1*32768 + w*2048;
    gl2lds16(r0p + so, d0);  gl2lds16(r0p + 1024 + so, d0 + 1024);
    gl2lds16(r1p + so, d1);  gl2lds16(r1p + 1024 + so, d1 + 1024);
  }

  // init v
  v4f v0, v1;
  if (fwd) {
    v0 = (v4f){1.f,1.f,1.f,1.f}; v1 = v0;
  } else {
    const float* ip = logit + (size_t)(cgc*CH + CH - 1)*L + jrow0;
    float4 x0 = *(const float4*)ip, x1 = *(const float4*)(ip + 16);
    v0 = (v4f){__expf(x0.x),__expf(x0.y),__expf(x0.z),__expf(x0.w)};
    v1 = (v4f){__expf(x1.x),__expf(x1.y),__expf(x1.z),__expf(x1.w)};
  }
  float m = 0.0f;
  int par = 0;
  int bo0 = 0, bo1 = 32768, bo2 = 2*32768;

  // initial renorm -> Pl[0]
  {
    float mx = fmaxf(fmaxf(fmaxf(v0[0],v0[1]),fmaxf(v0[2],v0[3])),
                     fmaxf(fmaxf(v1[0],v1[1]),fmaxf(v1[2],v1[3])));
    mx = fmaxf(mx, __shfl_xor(mx, 16));
    mx = fmaxf(mx, __shfl_xor(mx, 32));
    if (quad == 0) sPart[cl][w] = mx;
    lds_sync();
    const float4* sp4 = (const float4*)&sPart[cl][0];
    float4 q0 = sp4[0], q1 = sp4[1], q2 = sp4[2], q3 = sp4[3];
    float M = fmaxf(fmaxf(fmaxf(fmaxf(q0.x,q0.y),fmaxf(q0.z,q0.w)),
                          fmaxf(fmaxf(q1.x,q1.y),fmaxf(q1.z,q1.w))),
                    fmaxf(fmaxf(fmaxf(q2.x,q2.y),fmaxf(q2.z,q2.w)),
                          fmaxf(fmaxf(q3.x,q3.y),fmaxf(q3.z,q3.w))));
    float sc = 448.0f / M;
    int u0 = __builtin_amdgcn_cvt_pk_fp8_f32(v0[0]*sc, v0[1]*sc, 0, false);
    u0     = __builtin_amdgcn_cvt_pk_fp8_f32(v0[2]*sc, v0[3]*sc, u0, true);
    *(int*)&Pl[pladdr0] = u0;
    int u1 = __builtin_amdgcn_cvt_pk_fp8_f32(v1[0]*sc, v1[1]*sc, 0, false);
    u1     = __builtin_amdgcn_cvt_pk_fp8_f32(v1[2]*sc, v1[3]*sc, u1, true);
    *(int*)&Pl[pladdr1] = u1;
    m = __logf(M) - LN448;
    step_sync();                       // vmcnt(2): step-0 staging complete
  }

  for (int k = 0; k < CH; ++k) {
    const bool last = (k == CH-1);
    const bool useF = fwd || !last;

    // stage step k+2 into bo2 (buffer freed by step k-1's reads)
    {
      const int ks = k + 2;
      const bool ok = fwd ? (ks <= CH-1) : (ks <= CH-2);
      if (ok) {
        size_t t = (size_t)(fwd ? (cgcw*CH + ks) : (cgcw*CH + CH - 2 - ks));
        const char* row = (const char*)logit + t*(L*4);
        char* dst = LF + bo2 + w*2048;
        gl2lds16(row + so, dst);
        gl2lds16(row + 1024 + so, dst + 1024);
      }
    }

    // MFMA burst: full 512-row matvec for the 16 columns
    v4f a0 = (v4f){0.f,0.f,0.f,0.f};
    v4f a1 = (v4f){0.f,0.f,0.f,0.f};
    {
      const unsigned char* plr = Pl + par*8192 + bbbase;
      #pragma unroll
      for (int kt = 0; kt < 16; ++kt) {
        long bb = *(const long*)(plr + kt*512);
        a0 = __builtin_amdgcn_mfma_f32_16x16x32_fp8_fp8(eA[0][kt], bb, a0, 0, 0, 0);
        a1 = __builtin_amdgcn_mfma_f32_16x16x32_fp8_fp8(eA[1][kt], bb, a1, 0, 0, 0);
      }
    }

    if (useF) {
      const char* fb = LF + bo0;
      float4 q0 = *(const float4*)(fb + fa0);
      float4 q1 = *(const float4*)(fb + fa1);
      float f0=__expf(q0.x), f1=__expf(q0.y), f2=__expf(q0.z), f3=__expf(q0.w);
      float g0=__expf(q1.x), g1=__expf(q1.y), g2=__expf(q1.z), g3=__expf(q1.w);
      a0 = (v4f){a0[0]*f0, a0[1]*f1, a0[2]*f2, a0[3]*f3};
      a1 = (v4f){a1[0]*g0, a1[1]*g1, a1[2]*g2, a1[3]*g3};
      if (k == 0 && isc0) {          // chunk 0 exact anchor: alpha_0 = exp(feat_0)
        a0 = (v4f){f0,f1,f2,f3}; a1 = (v4f){g0,g1,g2,g3}; m = 0.0f;
      }
    }

    if (last) {
      if (cg <= NCF-1) {
        // folded E'=2E compensation: 16 steps (15 for the anchored chunk)
        float madj = m - (isc0 ? (float)(CH-1) : (float)CH) * LN2;
        unsigned short* dst = (fwd ? G : H) + (size_t)cg*L + jrow0;
        unsigned long long pv =
             (unsigned long long)f2b(__logf(a0[0]) + madj)
          | ((unsigned long long)f2b(__logf(a0[1]) + madj) << 16)
          | ((unsigned long long)f2b(__logf(a0[2]) + madj) << 32)
          | ((unsigned long long)f2b(__logf(a0[3]) + madj) << 48);
        *(unsigned long long*)dst = pv;
        pv = (unsigned long long)f2b(__logf(a1[0]) + madj)
          | ((unsigned long long)f2b(__logf(a1[1]) + madj) << 16)
          | ((unsigned long long)f2b(__logf(a1[2]) + madj) << 32)
          | ((unsigned long long)f2b(__logf(a1[3]) + madj) << 48);
        *(unsigned long long*)(dst + 16) = pv;
      }
    } else {
      // renorm + fp8 quantize into Pl[par^1]
      float mx = fmaxf(fmaxf(fmaxf(a0[0],a0[1]),fmaxf(a0[2],a0[3])),
                       fmaxf(fmaxf(a1[0],a1[1]),fmaxf(a1[2],a1[3])));
      mx = fmaxf(mx, __shfl_xor(mx, 16));
      mx = fmaxf(mx, __shfl_xor(mx, 32));
      if (quad == 0) sPart[cl][w] = mx;
      lds_sync();
      const float4* sp4 = (const float4*)&sPart[cl][0];
      float4 q0 = sp4[0], q1 = sp4[1], q2 = sp4[2], q3 = sp4[3];
      float M = fmaxf(fmaxf(fmaxf(fmaxf(q0.x,q0.y),fmaxf(q0.z,q0.w)),
                            fmaxf(fmaxf(q1.x,q1.y),fmaxf(q1.z,q1.w))),
                      fmaxf(fmaxf(fmaxf(q2.x,q2.y),fmaxf(q2.z,q2.w)),
                            fmaxf(fmaxf(q3.x,q3.y),fmaxf(q3.z,q3.w))));
      float sc = 448.0f / M;
      int u0 = __builtin_amdgcn_cvt_pk_fp8_f32(a0[0]*sc, a0[1]*sc, 0, false);
      u0     = __builtin_amdgcn_cvt_pk_fp8_f32(a0[2]*sc, a0[3]*sc, u0, true);
      *(int*)&Pl[(par^1)*8192 + pladdr0] = u0;
      int u1 = __builtin_amdgcn_cvt_pk_fp8_f32(a1[0]*sc, a1[1]*sc, 0, false);
      u1     = __builtin_amdgcn_cvt_pk_fp8_f32(a1[2]*sc, a1[3]*sc, u1, true);
      *(int*)&Pl[(par^1)*8192 + pladdr1] = u1;
      m += __logf(M) - LN448;
      step_sync();                     // Pl visible; keep 2 staging in flight
      par ^= 1;
      int tmp = bo0; bo0 = bo1; bo1 = bo2; bo2 = tmp;
    }
  }
}

// ---------------- lse: stitch terms — one WAVE per chunk ----------------
extern "C" __global__ __launch_bounds__(512)
void crf_lse(const unsigned short* __restrict__ G,
             const unsigned short* __restrict__ H,
             float* __restrict__ lsebuf){
  const int tidx = threadIdx.x;
  const int w    = tidx >> 6;
  const int lane = tidx & 63;
  const int g    = blockIdx.x*8 + w;             // 0..2047
  const int j8   = lane*8;
  if (g == 0) {
    const unsigned short* p = G + (size_t)(NCF-1)*L + j8;
    ushort4 a = *(const ushort4*)p, bq = *(const ushort4*)(p + 4);
    float v[8] = { b2f(a.x),b2f(a.y),b2f(a.z),b2f(a.w),
                   b2f(bq.x),b2f(bq.y),b2f(bq.z),b2f(bq.w) };
    float mx = v[0];
    #pragma unroll
    for (int r = 1; r < 8; ++r) mx = fmaxf(mx, v[r]);
    mx = waveMax(mx);
    float s = 0.f;
    #pragma unroll
    for (int r = 0; r < 8; ++r) s += __expf(v[r] - mx);
    s = waveSum(s);
    if (lane == 0) lsebuf[2*NCF] = mx + __logf(s);
  } else {
    const unsigned short* hp = H + (size_t)g*L + j8;
    const unsigned short* gp = G + (size_t)(g-1)*L + j8;
    ushort4 ha = *(const ushort4*)hp, hb = *(const ushort4*)(hp + 4);
    ushort4 ga = *(const ushort4*)gp, gb = *(const ushort4*)(gp + 4);
    float hv[8] = { b2f(ha.x),b2f(ha.y),b2f(ha.z),b2f(ha.w),
                    b2f(hb.x),b2f(hb.y),b2f(hb.z),b2f(hb.w) };
    float gv[8] = { b2f(ga.x),b2f(ga.y),b2f(ga.z),b2f(ga.w),
                    b2f(gb.x),b2f(gb.y),b2f(gb.z),b2f(gb.w) };
    float m1 = -3.0e38f, m2 = -3.0e38f;
    #pragma unroll
    for (int r = 0; r < 8; ++r) {
      float a = hv[r] + gv[r];
      m1 = fmaxf(m1, a); m2 = fmaxf(m2, hv[r]);
    }
    m1 = waveMax(m1); m2 = waveMax(m2);
    float s1 = 0.f, s2 = 0.f;
    #pragma unroll
    for (int r = 0; r < 8; ++r) {
      s1 += __expf(hv[r] + gv[r] - m1);
      s2 += __expf(hv[r] - m2);
    }
    s1 = waveSum(s1); s2 = waveSum(s2);
    if (lane == 0) {
      lsebuf[g]       = m1 + __logf(s1);
      lsebuf[NCF + g] = m2 + __logf(s2);
    }
  }
}

// ---------------- final: logZ - gold ----------------
extern "C" __global__ __launch_bounds__(512)
void crf_final(const float* __restrict__ lsebuf,
               const float* __restrict__ part,
               float* __restrict__ out){
  __shared__ float sredG[9];
  const int tidx = threadIdx.x;
  float acc = 0.f;
  #pragma unroll
  for (int c = tidx; c < NCF; c += 512)
    if (c >= 1) acc += lsebuf[c] - lsebuf[NCF + c];
  if (tidx < NB) acc -= part[tidx];
  float s = blockSum8(acc, sredG);
  if (tidx == 0) out[0] = lsebuf[2*NCF] + s;
}

extern "C" void kernel_launch(void* const* d_in, const int* in_sizes, int n_in,
                              void* d_out, int out_size, void* d_ws, size_t ws_size,
                              hipStream_t stream){
  const float* logit = (const float*)d_in[0];
  const int* labels  = (const int*)d_in[1];
  const float* T     = (const float*)d_in[2];
  float* out = (float*)d_out;
  char* ws = (char*)d_ws;
  unsigned char* EAf = (unsigned char*)(ws + OFF_EAF);
  unsigned char* EAb = (unsigned char*)(ws + OFF_EAB);
  unsigned short* G  = (unsigned short*)(ws + OFF_G);
  unsigned short* H  = (unsigned short*)(ws + OFF_H);
  float* lsebuf = (float*)(ws + OFF_LSE);
  float* part   = (float*)(ws + OFF_GOLD);

  static bool attr_set = false;
  if (!attr_set) {
    (void)hipFuncSetAttribute((const void*)crf_chunks,
                        hipFuncAttributeMaxDynamicSharedMemorySize, SMEM_TOTAL);
    attr_set = true;
  }

  crf_prep  <<<NB, TPB, 0, stream>>>(logit, labels, T, EAf, EAb, part);
  crf_chunks<<<NB, TPB, SMEM_TOTAL, stream>>>(logit, EAf, EAb, G, H);
  crf_lse   <<<NB, 512, 0, stream>>>(G, H, lsebuf);
  crf_final <<<1, 512, 0, stream>>>(lsebuf, part, out);
}